// Round 6
// baseline (3431.636 us; speedup 1.0000x reference)
//
#include <hip/hip_runtime.h>
#include <cstdint>
#include <cstddef>

#define T_STEPS 1000
#define NS      512
#define HID     128
#define DOUT    20
#define XPAD    129   // x tile row pad (dense kernel)
#define PSTR    130   // paired-LDS row stride in dwords (128 pairs + 2 pad)
#define SPMM_R  32    // rows per wave in spmm
#define SPW     4     // samples per wave (recur kernels)

// ---------------------------------------------------------------------------
// P0: dense precompute D[row][o] = dot(x_row, Wi1[o][:]). Bit-exact 4-acc
// stride-4 fmaf chain (verified absmax=0.0 rounds 1-5). DO NOT reorder.
// ---------------------------------------------------------------------------
extern "C" __global__ void __launch_bounds__(512, 1)
srnn_dense(const float* __restrict__ x, const float* __restrict__ Wi1,
           float* __restrict__ D, int t0, int Tc)
{
    extern __shared__ float sm[];
    float* xs = sm;                    // [128 rows][XPAD]
    float* Wl = sm + 128 * XPAD;       // Wi1 row-major [128][128]
    const int tid = threadIdx.x;
    const int w = tid >> 6, ln = tid & 63;
    const int rb = blockIdx.x * 128;

    for (int i = tid; i < HID * HID / 4; i += 512)
        ((float4*)Wl)[i] = ((const float4*)Wi1)[i];
    for (int i = tid; i < 128 * 32; i += 512) {
        int r = i >> 5, kq = i & 31;
        int cr = rb + r;
        int s = cr / Tc, trel = cr - s * Tc;
        float4 v = ((const float4*)x)[((size_t)s * T_STEPS + t0 + trel) * 32 + kq];
        float* dst = &xs[r * XPAD + 4 * kq];
        dst[0] = v.x; dst[1] = v.y; dst[2] = v.z; dst[3] = v.w;
    }
    __syncthreads();

    const float* xr0 = xs + ln * XPAD;
    const float* xr1 = xs + (64 + ln) * XPAD;
    for (int og = 0; og < 4; ++og) {
        const int o = 16 * w + 4 * og;
        float a[2][4][4];
        #pragma unroll
        for (int r = 0; r < 2; ++r)
            #pragma unroll
            for (int j = 0; j < 4; ++j)
                #pragma unroll
                for (int i = 0; i < 4; ++i) a[r][j][i] = 0.f;

        #pragma unroll 4
        for (int k = 0; k < HID; k += 4) {
            float4 wv[4];
            #pragma unroll
            for (int j = 0; j < 4; ++j)
                wv[j] = *(const float4*)&Wl[(o + j) * HID + k];
            float xa0[4], xa1[4];
            #pragma unroll
            for (int i = 0; i < 4; ++i) { xa0[i] = xr0[k + i]; xa1[i] = xr1[k + i]; }
            #pragma unroll
            for (int j = 0; j < 4; ++j) {
                a[0][j][0] = fmaf(xa0[0], wv[j].x, a[0][j][0]);
                a[0][j][1] = fmaf(xa0[1], wv[j].y, a[0][j][1]);
                a[0][j][2] = fmaf(xa0[2], wv[j].z, a[0][j][2]);
                a[0][j][3] = fmaf(xa0[3], wv[j].w, a[0][j][3]);
                a[1][j][0] = fmaf(xa1[0], wv[j].x, a[1][j][0]);
                a[1][j][1] = fmaf(xa1[1], wv[j].y, a[1][j][1]);
                a[1][j][2] = fmaf(xa1[2], wv[j].z, a[1][j][2]);
                a[1][j][3] = fmaf(xa1[3], wv[j].w, a[1][j][3]);
            }
        }
        #pragma unroll
        for (int r = 0; r < 2; ++r) {
            float4 dv;
            dv.x = (a[r][0][0] + a[r][0][1]) + (a[r][0][2] + a[r][0][3]);
            dv.y = (a[r][1][0] + a[r][1][1]) + (a[r][1][2] + a[r][1][3]);
            dv.z = (a[r][2][0] + a[r][2][1]) + (a[r][2][2] + a[r][2][3]);
            dv.w = (a[r][3][0] + a[r][3][1]) + (a[r][3][2] + a[r][3][3]);
            *(float4*)&D[(size_t)(rb + 64 * r + ln) * HID + o] = dv;
        }
    }
}

// ---------------------------------------------------------------------------
// Paired-LDS staging: WT2[j*PSTR + 2*l + h] = W[h*64+l][j]; row 128 = zeros.
// One ds_read_b64 yields (W^T[j][l], W^T[j][l+64]) for lane l.
// ---------------------------------------------------------------------------
__device__ __forceinline__ void stage_paired(float* __restrict__ WT2,
                                             const float* __restrict__ W,
                                             int tid, int nthreads)
{
    for (int i = tid; i < HID * HID / 4; i += nthreads) {
        int o = i >> 5, jq = i & 31;
        float4 v = ((const float4*)W)[i];
        int c = 2 * (o & 63) + (o >> 6);
        WT2[(4 * jq + 0) * PSTR + c] = v.x;
        WT2[(4 * jq + 1) * PSTR + c] = v.y;
        WT2[(4 * jq + 2) * PSTR + c] = v.z;
        WT2[(4 * jq + 3) * PSTR + c] = v.w;
    }
    for (int i = tid; i < PSTR; i += nthreads) WT2[128 * PSTR + i] = 0.f;
}

// Pop up to 4 ascending set bits (pad 128 -> zero row, +0.0f exact identity).
// mm &= mm-1 is safe at mm==0 (0 & ~0 = 0).
__device__ __forceinline__ void pop4(unsigned long long& mm, int base, int j[4])
{
    j[0] = mm ? (int)__builtin_ctzll(mm) + base : 128; mm &= mm - 1;
    j[1] = mm ? (int)__builtin_ctzll(mm) + base : 128; mm &= mm - 1;
    j[2] = mm ? (int)__builtin_ctzll(mm) + base : 128; mm &= mm - 1;
    j[3] = mm ? (int)__builtin_ctzll(mm) + base : 128; mm &= mm - 1;
}

// Sparse paired sum for one mask (used by spmm). Frozen bit-exact order.
__device__ __forceinline__ void sparse4p(const float* __restrict__ WT2,
                                         unsigned long long mm, int base,
                                         int ln2, float& rl, float& rh)
{
    while (mm) {
        int j[4]; pop4(mm, base, j);
        float2 p0 = *(const float2*)&WT2[j[0] * PSTR + ln2];
        float2 p1 = *(const float2*)&WT2[j[1] * PSTR + ln2];
        float2 p2 = *(const float2*)&WT2[j[2] * PSTR + ln2];
        float2 p3 = *(const float2*)&WT2[j[3] * PSTR + ln2];
        rl += p0.x; rl += p1.x; rl += p2.x; rl += p3.x;
        rh += p0.y; rh += p1.y; rh += p2.y; rh += p3.y;
    }
}

// Combined sparse sum over SPW samples: each iteration pops <=4 bits from
// EVERY sample's mask and issues all 16 b64 loads together — 4 independent
// latency chains overlap. Per-sample add order identical to sparse4p
// (ascending 4-groups, +0.0 pads; exhausted samples add +0.0 only).
__device__ __forceinline__ void sparse_multi(const float* __restrict__ WT2,
                                             unsigned long long a[SPW], int base,
                                             int ln2, float rl[SPW], float rh[SPW])
{
    while (a[0] | a[1] | a[2] | a[3]) {
        int j0[4], j1[4], j2[4], j3[4];
        pop4(a[0], base, j0); pop4(a[1], base, j1);
        pop4(a[2], base, j2); pop4(a[3], base, j3);
        float2 p0[4], p1[4], p2[4], p3[4];
        #pragma unroll
        for (int k = 0; k < 4; ++k) {
            p0[k] = *(const float2*)&WT2[j0[k] * PSTR + ln2];
            p1[k] = *(const float2*)&WT2[j1[k] * PSTR + ln2];
            p2[k] = *(const float2*)&WT2[j2[k] * PSTR + ln2];
            p3[k] = *(const float2*)&WT2[j3[k] * PSTR + ln2];
        }
        rl[0] += p0[0].x; rl[0] += p0[1].x; rl[0] += p0[2].x; rl[0] += p0[3].x;
        rh[0] += p0[0].y; rh[0] += p0[1].y; rh[0] += p0[2].y; rh[0] += p0[3].y;
        rl[1] += p1[0].x; rl[1] += p1[1].x; rl[1] += p1[2].x; rl[1] += p1[3].x;
        rh[1] += p1[0].y; rh[1] += p1[1].y; rh[1] += p1[2].y; rh[1] += p1[3].y;
        rl[2] += p2[0].x; rl[2] += p2[1].x; rl[2] += p2[2].x; rl[2] += p2[3].x;
        rh[2] += p2[0].y; rh[2] += p2[1].y; rh[2] += p2[2].y; rh[2] += p2[3].y;
        rl[3] += p3[0].x; rl[3] += p3[1].x; rl[3] += p3[2].x; rl[3] += p3[3].x;
        rh[3] += p3[0].y; rh[3] += p3[1].y; rh[3] += p3[2].y; rh[3] += p3[3].y;
    }
}

// ---------------------------------------------------------------------------
// P1: layer-1 serial recurrence, SPW samples per wave (cross-sample latency
// interleave). Lane owns neurons {ln, 64+ln} of each of its 4 samples.
// ---------------------------------------------------------------------------
extern "C" __global__ void __launch_bounds__(256, 1)
srnn_recur1(const float* __restrict__ Dn, const float* __restrict__ Wh,
            const float* __restrict__ bi, const float* __restrict__ bh,
            ulonglong2* __restrict__ masks, ulonglong2* __restrict__ state,
            int t0, int Tc, int first)
{
    extern __shared__ float WT2[];     // [129][PSTR] paired, row 128 zeros
    const int tid = threadIdx.x, w = tid >> 6, ln = tid & 63, ln2 = 2 * ln;
    const int sbase = blockIdx.x * (4 * SPW) + w * SPW;

    stage_paired(WT2, Wh, tid, 256);
    const float bil = bi[ln], bih = bi[64 + ln];
    const float bhl = bh[ln], bhh = bh[64 + ln];

    unsigned long long M0[SPW], M1[SPW];
    #pragma unroll
    for (int q = 0; q < SPW; ++q) { M0[q] = 0ULL; M1[q] = 0ULL; }
    if (!first) {
        #pragma unroll
        for (int q = 0; q < SPW; ++q) {
            ulonglong2 st = state[sbase + q]; M0[q] = st.x; M1[q] = st.y;
        }
    }
    __syncthreads();

    const float* Dr[SPW];
    #pragma unroll
    for (int q = 0; q < SPW; ++q) Dr[q] = Dn + (size_t)(sbase + q) * Tc * HID;

    // depth-2 dense-term prefetch (constant-indexed, fully unrolled)
    float c0l[SPW], c0h[SPW], c1l[SPW], c1h[SPW];
    const int t1i = (1 < Tc) ? 1 : Tc - 1;
    #pragma unroll
    for (int q = 0; q < SPW; ++q) {
        c0l[q] = Dr[q][ln];                c0h[q] = Dr[q][64 + ln];
        c1l[q] = Dr[q][t1i * HID + ln];    c1h[q] = Dr[q][t1i * HID + 64 + ln];
    }

    for (int t = 0; t < Tc; ++t) {
        const int tn = (t + 2 < Tc) ? t + 2 : Tc - 1;   // issue D(t+2)
        float c2l[SPW], c2h[SPW];
        #pragma unroll
        for (int q = 0; q < SPW; ++q) {
            c2l[q] = Dr[q][tn * HID + ln];
            c2h[q] = Dr[q][tn * HID + 64 + ln];
        }

        float rl[SPW], rh[SPW];
        #pragma unroll
        for (int q = 0; q < SPW; ++q) { rl[q] = 0.f; rh[q] = 0.f; }
        unsigned long long a[SPW];
        #pragma unroll
        for (int q = 0; q < SPW; ++q) a[q] = M0[q];
        sparse_multi(WT2, a, 0, ln2, rl, rh);           // half 0 (frozen order)
        #pragma unroll
        for (int q = 0; q < SPW; ++q) a[q] = M1[q];
        sparse_multi(WT2, a, 64, ln2, rl, rh);          // half 1

        #pragma unroll
        for (int q = 0; q < SPW; ++q) {
            float hl = ((c0l[q] + bil) + rl[q]) + bhl;  // reference add order
            float hh = ((c0h[q] + bih) + rh[q]) + bhh;
            M0[q] = __ballot(hl >= 1.0f);
            M1[q] = __ballot(hh >= 1.0f);
        }
        // lanes 0..3 each store one sample's mask
        unsigned long long lo = M0[0], hi = M1[0];
        if (ln == 1) { lo = M0[1]; hi = M1[1]; }
        if (ln == 2) { lo = M0[2]; hi = M1[2]; }
        if (ln == 3) { lo = M0[3]; hi = M1[3]; }
        if (ln < SPW) {
            ulonglong2 mv; mv.x = lo; mv.y = hi;
            masks[(size_t)(sbase + ln) * T_STEPS + (t0 + t)] = mv;
        }
        #pragma unroll
        for (int q = 0; q < SPW; ++q) {
            c0l[q] = c1l[q]; c0h[q] = c1h[q];
            c1l[q] = c2l[q]; c1h[q] = c2h[q];
        }
    }
    if (ln == 0) {
        #pragma unroll
        for (int q = 0; q < SPW; ++q) {
            ulonglong2 st; st.x = M0[q]; st.y = M1[q]; state[sbase + q] = st;
        }
    }
}

// ---------------------------------------------------------------------------
// P2: parallel sparse matmul D2[s,t,:] = s1(s,t)@Wi2^T. 32 rows/wave after
// one staging. Ascending single-accumulator order (frozen).
// ---------------------------------------------------------------------------
extern "C" __global__ void __launch_bounds__(256, 1)
srnn_spmm(const ulonglong2* __restrict__ masks1, const float* __restrict__ Wi2,
          float* __restrict__ D2, int t0, int Tc)
{
    extern __shared__ float WI2[];     // [129][PSTR] paired
    const int tid = threadIdx.x, w = tid >> 6, ln = tid & 63, ln2 = 2 * ln;
    stage_paired(WI2, Wi2, tid, 256);
    __syncthreads();

    const int s = blockIdx.y;
    const int tbase = (blockIdx.x * 4 + w) * SPMM_R;
    if (tbase >= Tc) return;
    const ulonglong2* mrow = masks1 + (size_t)s * T_STEPS + t0;

    ulonglong2 m = mrow[tbase];
    for (int r = 0; r < SPMM_R; ++r) {
        int trel = tbase + r;
        if (trel >= Tc) break;                     // wave-uniform
        ulonglong2 cm = m;
        if (r + 1 < SPMM_R && trel + 1 < Tc) m = mrow[trel + 1];

        float Al = 0.f, Ah = 0.f;
        sparse4p(WI2, cm.x, 0,  ln2, Al, Ah);
        sparse4p(WI2, cm.y, 64, ln2, Al, Ah);

        size_t ro = ((size_t)s * Tc + trel) * HID;
        D2[ro + ln] = Al;
        D2[ro + 64 + ln] = Ah;
    }
}

// ---------------------------------------------------------------------------
// P3: layer-2 serial recurrence + fused output accumulation, SPW samples per
// wave. Wo dot uses the same combined multi-sample pop pattern (frozen order:
// p0-half groups then p1-half groups, d += w0..w3 ascending).
// ---------------------------------------------------------------------------
extern "C" __global__ void __launch_bounds__(256, 1)
srnn_recur2(const float* __restrict__ D2, const float* __restrict__ Wh2,
            const float* __restrict__ bi2, const float* __restrict__ bh2,
            const float* __restrict__ Wo,  const float* __restrict__ bo,
            ulonglong2* __restrict__ state, float* __restrict__ accst,
            float* __restrict__ out, int t0, int Tc, int first, int last)
{
    extern __shared__ float sm2[];
    float* WT2 = sm2;                  // Wh2 paired [129][PSTR], row 128 zeros
    float* WOt = sm2 + 129 * PSTR;     // Wo^T [129][DOUT], row 128 zeros
    const int tid = threadIdx.x, w = tid >> 6, ln = tid & 63, ln2 = 2 * ln;
    const int sbase = blockIdx.x * (4 * SPW) + w * SPW;

    stage_paired(WT2, Wh2, tid, 256);
    for (int i = tid; i < DOUT * HID / 4; i += 256) {
        int o = i >> 5, jq = i & 31;
        float4 v = ((const float4*)Wo)[i];
        WOt[(4 * jq + 0) * DOUT + o] = v.x; WOt[(4 * jq + 1) * DOUT + o] = v.y;
        WOt[(4 * jq + 2) * DOUT + o] = v.z; WOt[(4 * jq + 3) * DOUT + o] = v.w;
    }
    for (int i = tid; i < DOUT; i += 256) WOt[128 * DOUT + i] = 0.f;

    const float bil = bi2[ln], bih = bi2[64 + ln];
    const float bhl = bh2[ln], bhh = bh2[64 + ln];
    const bool  oth = (ln < DOUT);
    const int   c   = oth ? ln : 0;
    const float bov = oth ? bo[ln] : 0.f;

    unsigned long long M0[SPW], M1[SPW];
    float acc[SPW];
    #pragma unroll
    for (int q = 0; q < SPW; ++q) { M0[q] = 0ULL; M1[q] = 0ULL; acc[q] = 0.f; }
    if (!first) {
        #pragma unroll
        for (int q = 0; q < SPW; ++q) {
            ulonglong2 st = state[sbase + q]; M0[q] = st.x; M1[q] = st.y;
            if (oth) acc[q] = accst[(sbase + q) * DOUT + ln];
        }
    }
    __syncthreads();

    const float* Dr[SPW];
    #pragma unroll
    for (int q = 0; q < SPW; ++q) Dr[q] = D2 + (size_t)(sbase + q) * Tc * HID;

    float c0l[SPW], c0h[SPW], c1l[SPW], c1h[SPW];
    const int t1i = (1 < Tc) ? 1 : Tc - 1;
    #pragma unroll
    for (int q = 0; q < SPW; ++q) {
        c0l[q] = Dr[q][ln];                c0h[q] = Dr[q][64 + ln];
        c1l[q] = Dr[q][t1i * HID + ln];    c1h[q] = Dr[q][t1i * HID + 64 + ln];
    }

    for (int t = 0; t < Tc; ++t) {
        const int tn = (t + 2 < Tc) ? t + 2 : Tc - 1;
        float c2l[SPW], c2h[SPW];
        #pragma unroll
        for (int q = 0; q < SPW; ++q) {
            c2l[q] = Dr[q][tn * HID + ln];
            c2h[q] = Dr[q][tn * HID + 64 + ln];
        }

        float Bl[SPW], Bh[SPW];
        #pragma unroll
        for (int q = 0; q < SPW; ++q) { Bl[q] = 0.f; Bh[q] = 0.f; }
        unsigned long long a[SPW];
        #pragma unroll
        for (int q = 0; q < SPW; ++q) a[q] = M0[q];
        sparse_multi(WT2, a, 0, ln2, Bl, Bh);
        #pragma unroll
        for (int q = 0; q < SPW; ++q) a[q] = M1[q];
        sparse_multi(WT2, a, 64, ln2, Bl, Bh);

        #pragma unroll
        for (int q = 0; q < SPW; ++q) {
            float hl = ((c0l[q] + bil) + Bl[q]) + bhl;  // reference add order
            float hh = ((c0h[q] + bih) + Bh[q]) + bhh;
            M0[q] = __ballot(hl >= 1.0f);
            M1[q] = __ballot(hh >= 1.0f);
        }

        // fused s2@Wo^T + bo — combined pops, frozen per-sample order
        float d[SPW];
        #pragma unroll
        for (int q = 0; q < SPW; ++q) d[q] = 0.f;
        #pragma unroll
        for (int half = 0; half < 2; ++half) {
            unsigned long long b0 = half ? M1[0] : M0[0];
            unsigned long long b1 = half ? M1[1] : M0[1];
            unsigned long long b2 = half ? M1[2] : M0[2];
            unsigned long long b3 = half ? M1[3] : M0[3];
            const int base = half ? 64 : 0;
            while (b0 | b1 | b2 | b3) {
                int j0[4], j1[4], j2[4], j3[4];
                pop4(b0, base, j0); pop4(b1, base, j1);
                pop4(b2, base, j2); pop4(b3, base, j3);
                float w0[4], w1[4], w2[4], w3[4];
                #pragma unroll
                for (int k = 0; k < 4; ++k) {
                    w0[k] = WOt[j0[k] * DOUT + c];
                    w1[k] = WOt[j1[k] * DOUT + c];
                    w2[k] = WOt[j2[k] * DOUT + c];
                    w3[k] = WOt[j3[k] * DOUT + c];
                }
                d[0] += w0[0]; d[0] += w0[1]; d[0] += w0[2]; d[0] += w0[3];
                d[1] += w1[0]; d[1] += w1[1]; d[1] += w1[2]; d[1] += w1[3];
                d[2] += w2[0]; d[2] += w2[1]; d[2] += w2[2]; d[2] += w2[3];
                d[3] += w3[0]; d[3] += w3[1]; d[3] += w3[2]; d[3] += w3[3];
            }
        }
        #pragma unroll
        for (int q = 0; q < SPW; ++q) {
            if (oth) { acc[q] += d[q]; acc[q] += bov; }  // (acc + dot) + bo
        }

        #pragma unroll
        for (int q = 0; q < SPW; ++q) {
            c0l[q] = c1l[q]; c0h[q] = c1h[q];
            c1l[q] = c2l[q]; c1h[q] = c2h[q];
        }
    }
    if (ln == 0) {
        #pragma unroll
        for (int q = 0; q < SPW; ++q) {
            ulonglong2 st; st.x = M0[q]; st.y = M1[q]; state[sbase + q] = st;
        }
    }
    if (oth) {
        #pragma unroll
        for (int q = 0; q < SPW; ++q) {
            if (last) out[(sbase + q) * DOUT + ln] = acc[q] / (float)T_STEPS;
            else      accst[(sbase + q) * DOUT + ln] = acc[q];
        }
    }
}

// ---------------------------------------------------------------------------
extern "C" void kernel_launch(void* const* d_in, const int* in_sizes, int n_in,
                              void* d_out, int out_size, void* d_ws, size_t ws_size,
                              hipStream_t stream) {
    const float* x   = (const float*)d_in[0];
    const float* Wi1 = (const float*)d_in[1];
    const float* bi1 = (const float*)d_in[2];
    const float* Wh1 = (const float*)d_in[3];
    const float* bh1 = (const float*)d_in[4];
    const float* Wi2 = (const float*)d_in[5];
    const float* bi2 = (const float*)d_in[6];
    const float* Wh2 = (const float*)d_in[7];
    const float* bh2 = (const float*)d_in[8];
    const float* Wo  = (const float*)d_in[9];
    const float* bo  = (const float*)d_in[10];
    float* out = (float*)d_out;

    // ws: [masks1 8.19M][state 16K][accst 40K][D / D2 shared chunk buffer]
    const size_t mb = (size_t)NS * T_STEPS * sizeof(ulonglong2);
    ulonglong2* masks1 = (ulonglong2*)d_ws;
    ulonglong2* state  = (ulonglong2*)((char*)d_ws + mb);
    const size_t state_bytes = (size_t)2 * NS * sizeof(ulonglong2);
    float* accst = (float*)((char*)d_ws + mb + state_bytes);
    const size_t acc_bytes = (size_t)NS * DOUT * sizeof(float);
    float* Dbuf = (float*)((char*)d_ws + mb + state_bytes + acc_bytes);

    const size_t base = mb + state_bytes + acc_bytes;
    size_t avail = ws_size > base ? ws_size - base : 0;
    const size_t bytes_per_t = (size_t)NS * HID * sizeof(float);  // 256 KB
    long tcmax = (long)(avail / bytes_per_t);
    static const int divs[] = {1000, 500, 200, 100, 40, 20, 8, 4};
    int Tc = 4;
    for (int i = 0; i < 8; ++i) if (divs[i] <= tcmax) { Tc = divs[i]; break; }

    const int lds0 = (128 * XPAD + HID * HID) * (int)sizeof(float);
    const int ldsP = (129 * PSTR) * (int)sizeof(float);
    const int lds2 = (129 * PSTR + 129 * DOUT) * (int)sizeof(float);
    hipFuncSetAttribute((const void*)srnn_dense,
                        hipFuncAttributeMaxDynamicSharedMemorySize, lds0);
    hipFuncSetAttribute((const void*)srnn_recur1,
                        hipFuncAttributeMaxDynamicSharedMemorySize, ldsP);
    hipFuncSetAttribute((const void*)srnn_spmm,
                        hipFuncAttributeMaxDynamicSharedMemorySize, ldsP);
    hipFuncSetAttribute((const void*)srnn_recur2,
                        hipFuncAttributeMaxDynamicSharedMemorySize, lds2);

    const int rblocks = NS / (4 * SPW);   // 32 blocks, 256 threads, 4 samp/wave

    // Phase A: layer-1 (dense GEMM chunk -> serial recurrence chunk)
    for (int t0 = 0; t0 < T_STEPS; t0 += Tc) {
        srnn_dense<<<4 * Tc, 512, lds0, stream>>>(x, Wi1, Dbuf, t0, Tc);
        srnn_recur1<<<rblocks, 256, ldsP, stream>>>(Dbuf, Wh1, bi1, bh1,
                                                    masks1, state, t0, Tc, t0 == 0);
    }
    // Phase B: layer-2 (parallel spmm chunk -> serial recurrence + output)
    for (int t0 = 0; t0 < T_STEPS; t0 += Tc) {
        dim3 g2((Tc + 4 * SPMM_R - 1) / (4 * SPMM_R), NS);
        srnn_spmm<<<g2, 256, ldsP, stream>>>(masks1, Wi2, Dbuf, t0, Tc);
        srnn_recur2<<<rblocks, 256, lds2, stream>>>(Dbuf, Wh2, bi2, bh2, Wo, bo,
                                                    state + NS, accst, out,
                                                    t0, Tc, t0 == 0,
                                                    t0 + Tc >= T_STEPS);
    }
}